// Round 10
// baseline (377.041 us; speedup 1.0000x reference)
//
#include <hip/hip_runtime.h>
#include <hip/hip_bf16.h>
#include <math.h>

#define B_   2
#define L_   2048
#define E_   1024
#define H_   16
#define DH   64
#define DFF  4096
#define M_   4096
#define APAD 72
#define SCALE_Q 0.18033688011112042f   // log2(e)/8, folded into Wq/bq

typedef __attribute__((ext_vector_type(8))) short short8;
typedef __attribute__((ext_vector_type(4))) float f32x4;
typedef __bf16 bf16x8 __attribute__((ext_vector_type(8)));

__device__ __forceinline__ float bf2f(unsigned short u) {
    return __uint_as_float(((unsigned)u) << 16);
}
__device__ __forceinline__ unsigned short f2bf(float f) {
    unsigned u = __float_as_uint(f);
    return (unsigned short)((u + 0x7fff + ((u >> 16) & 1)) >> 16);
}
__device__ __forceinline__ unsigned pk_trunc(float lo, float hi) {
    return (__float_as_uint(lo) >> 16) | (__float_as_uint(hi) & 0xffff0000u);
}

// ---------------------------------------------------------------------------
// Fused preprocessing (task-decoded 1-D grid), unchanged.
// ---------------------------------------------------------------------------
__global__ __launch_bounds__(256) void prep(const float* __restrict__ x,
                                            const float* __restrict__ Wq,
                                            const float* __restrict__ Wk,
                                            const float* __restrict__ Wv,
                                            const float* __restrict__ bq,
                                            const float* __restrict__ bk,
                                            const float* __restrict__ bv,
                                            const float* __restrict__ Wo,
                                            const float* __restrict__ W1,
                                            const float* __restrict__ W2,
                                            unsigned short* __restrict__ xb,
                                            unsigned short* __restrict__ Wqkvt,
                                            unsigned short* __restrict__ Wot,
                                            unsigned short* __restrict__ W1t,
                                            unsigned short* __restrict__ W2t,
                                            float* __restrict__ bqkv) {
    __shared__ float tile[32][33];
    int bid = blockIdx.x;
    const int t = threadIdx.x;

    if (bid < 4096) {                      // x -> bf16
        int i = (bid * 256 + t) * 4;
        float4 v = *(const float4*)&x[i];
        ushort4 pk = { f2bf(v.x), f2bf(v.y), f2bf(v.z), f2bf(v.w) };
        *(ushort4*)&xb[i] = pk;
        return;
    }
    bid -= 4096;

    const float* in; unsigned short* outp; int R, C, r0, c0; float sc = 1.f;
    if (bid < 3072) {                      // Wqkv: per-head [E][DH] -> [DH][E]
        int xq = bid & 1, yq = (bid >> 1) & 31, wh = bid >> 6;
        int which = wh >> 4, h = wh & 15;
        in   = (which == 0 ? Wq : which == 1 ? Wk : Wv) + (size_t)h * E_ * DH;
        outp = Wqkvt + ((size_t)which * 1024 + h * 64) * 1024;
        R = E_; C = DH; r0 = yq * 32; c0 = xq * 32;
        if (which == 0) sc = SCALE_Q;
    } else if (bid < 4096) {               // Wo [E][E]
        bid -= 3072;
        in = Wo; outp = Wot; R = E_; C = E_;
        c0 = (bid & 31) * 32; r0 = (bid >> 5) * 32;
    } else if (bid < 8192) {               // W1 [E][DFF]
        bid -= 4096;
        in = W1; outp = W1t; R = E_; C = DFF;
        c0 = (bid & 127) * 32; r0 = (bid >> 7) * 32;
    } else if (bid < 12288) {              // W2 [DFF][E]
        bid -= 8192;
        in = W2; outp = W2t; R = DFF; C = E_;
        c0 = (bid & 31) * 32; r0 = (bid >> 5) * 32;
    } else {                               // bqkv
        bid -= 12288;
        int n = bid * 256 + t;
        bqkv[n] = n < 1024 ? bq[n] * SCALE_Q : n < 2048 ? bk[n - 1024] : bv[n - 2048];
        return;
    }

    const int tx = t & 31, tq = t >> 5;
#pragma unroll
    for (int s2 = 0; s2 < 4; s2++)
        tile[tq * 4 + s2][tx] = in[(size_t)(r0 + tq * 4 + s2) * C + c0 + tx] * sc;
    __syncthreads();
#pragma unroll
    for (int s2 = 0; s2 < 4; s2++)
        outp[(size_t)(c0 + tq * 4 + s2) * R + r0 + tx] = f2bf(tile[tx][tq * 4 + s2]);
}

// ---------------------------------------------------------------------------
// V pre-transpose with pi-permuted columns (unchanged).
// ---------------------------------------------------------------------------
__global__ __launch_bounds__(256) void v_transpose_perm(const unsigned short* __restrict__ qkv,
                                                        unsigned short* __restrict__ vtg) {
    __shared__ unsigned short tile[64 * APAD];
    const int t  = threadIdx.x;
    const int kt = blockIdx.x, hh = blockIdx.y, b = blockIdx.z;
    const int rr0 = t >> 3, o8 = (t & 7) * 8, rr1 = rr0 + 32;
    const size_t gbase = ((size_t)b * L_ + kt * 64) * 3072 + 2048 + hh * 64;
    *(short8*)&tile[rr0 * APAD + o8] = *(const short8*)&qkv[gbase + (size_t)rr0 * 3072 + o8];
    *(short8*)&tile[rr1 * APAD + o8] = *(const short8*)&qkv[gbase + (size_t)rr1 * 3072 + o8];
    __syncthreads();
    const size_t obase = ((size_t)(b * H_ + hh) * 64) * (size_t)L_ + kt * 64;
    const int a = t & 15, d0 = (t >> 4) * 4;
#pragma unroll
    for (int s2 = 0; s2 < 4; s2++) {
        int d = d0 + s2;
        ushort4 pk = { tile[(a +  0) * APAD + d], tile[(a + 16) * APAD + d],
                       tile[(a + 32) * APAD + d], tile[(a + 48) * APAD + d] };
        *(ushort4*)&vtg[obase + (size_t)d * L_ + 4 * a] = pk;
    }
}

// ---------------------------------------------------------------------------
// bf16 MFMA GEMM, B^T layout, 128x128, 2-deep register-prefetch pipeline:
// iter k issues load T(k+2), ds_writes T(k+1) (loaded a full iter ago),
// MFMAs on LDS[p]. Load->consume distance = 1 full iteration.
// XCD m-band swizzle. Grid = Nt*32 (1-D).
// ---------------------------------------------------------------------------
template <int RELU, int OUT_BF16>
__global__ __launch_bounds__(256) void gemm_bt(const unsigned short* __restrict__ A,
                                               const unsigned short* __restrict__ Bt,
                                               const float* __restrict__ bias,
                                               void* __restrict__ Cout,
                                               int M, int N, int K) {
    __shared__ __align__(16) unsigned short As[2][128 * 32];
    __shared__ __align__(16) unsigned short Bs[2][128 * 32];

    const int t    = threadIdx.x;
    const int lane = t & 63;
    const int w    = t >> 6;
    const int quad = lane >> 4;
    const int l16  = lane & 15;
    const int wm = (w >> 1) * 64, wn = (w & 1) * 64;

    const int lin = blockIdx.x;
    const int xcd = lin & 7, s = lin >> 3;
    const int n0 = (s >> 2) * 128;
    const int m0 = ((xcd << 2) | (s & 3)) * 128;
    const int rowA = t >> 2, offA = (t & 3) * 8, rowA2 = rowA + 64;
    const int la0 = rowA * 32 + offA, la1 = rowA2 * 32 + offA;

    const size_t aoff0 = (size_t)(m0 + rowA)  * K + offA;
    const size_t aoff1 = (size_t)(m0 + rowA2) * K + offA;
    const size_t boff0 = (size_t)(n0 + rowA)  * K + offA;
    const size_t boff1 = (size_t)(n0 + rowA2) * K + offA;

    f32x4 acc[4][4];
#pragma unroll
    for (int i = 0; i < 4; i++)
#pragma unroll
        for (int j = 0; j < 4; j++) acc[i][j] = (f32x4){0.f, 0.f, 0.f, 0.f};

    // prologue: T0 -> LDS[0]; T1 -> regs (cur)
    {
        short8 ta0 = *(const short8*)&A[aoff0];
        short8 ta1 = *(const short8*)&A[aoff1];
        short8 tb0 = *(const short8*)&Bt[boff0];
        short8 tb1 = *(const short8*)&Bt[boff1];
        *(short8*)&As[0][la0] = ta0;
        *(short8*)&As[0][la1] = ta1;
        *(short8*)&Bs[0][la0] = tb0;
        *(short8*)&Bs[0][la1] = tb1;
    }
    short8 ca0, ca1, cb0, cb1;     // T(k+1)
    if (32 < K) {
        ca0 = *(const short8*)&A[aoff0 + 32];
        ca1 = *(const short8*)&A[aoff1 + 32];
        cb0 = *(const short8*)&Bt[boff0 + 32];
        cb1 = *(const short8*)&Bt[boff1 + 32];
    }
    __syncthreads();

    int p = 0;
    for (int k0 = 0; k0 < K; k0 += 32, p ^= 1) {
        short8 na0, na1, nb0, nb1; // T(k+2)
        const bool have2 = (k0 + 64 < K);
        const bool have1 = (k0 + 32 < K);
        if (have2) {
            na0 = *(const short8*)&A[aoff0 + k0 + 64];
            na1 = *(const short8*)&A[aoff1 + k0 + 64];
            nb0 = *(const short8*)&Bt[boff0 + k0 + 64];
            nb1 = *(const short8*)&Bt[boff1 + k0 + 64];
        }
        if (have1) {   // stage T(k+1): its load completed ~1 iter ago
            *(short8*)&As[p ^ 1][la0] = ca0;
            *(short8*)&As[p ^ 1][la1] = ca1;
            *(short8*)&Bs[p ^ 1][la0] = cb0;
            *(short8*)&Bs[p ^ 1][la1] = cb1;
        }

        bf16x8 af[4], bfv[4];
#pragma unroll
        for (int i = 0; i < 4; i++)
            af[i] = *(const bf16x8*)&As[p][(wm + i * 16 + l16) * 32 + quad * 8];
#pragma unroll
        for (int j = 0; j < 4; j++)
            bfv[j] = *(const bf16x8*)&Bs[p][(wn + j * 16 + l16) * 32 + quad * 8];
#pragma unroll
        for (int i = 0; i < 4; i++)
#pragma unroll
            for (int j = 0; j < 4; j++)
                acc[i][j] = __builtin_amdgcn_mfma_f32_16x16x32_bf16(af[i], bfv[j], acc[i][j], 0, 0, 0);

        __syncthreads();
        if (have2) { ca0 = na0; ca1 = na1; cb0 = nb0; cb1 = nb1; }
    }

#pragma unroll
    for (int j = 0; j < 4; j++) {
        int col = n0 + wn + j * 16 + l16;
        float bv = bias[col];
#pragma unroll
        for (int i = 0; i < 4; i++) {
            int rowb = m0 + wm + i * 16 + quad * 4;
#pragma unroll
            for (int r = 0; r < 4; r++) {
                float v = acc[i][j][r] + bv;
                if (RELU) v = fmaxf(v, 0.f);
                if (OUT_BF16)
                    ((unsigned short*)Cout)[(size_t)(rowb + r) * N + col] = f2bf(v);
                else
                    ((float*)Cout)[(size_t)(rowb + r) * N + col] = v;
            }
        }
    }
}

// ---------------------------------------------------------------------------
// Split-K=4 GEMM, same 2-deep pipeline; bf16 partial planes. Grid = Nt*32*4.
// ---------------------------------------------------------------------------
__global__ __launch_bounds__(256) void gemm_sk4(const unsigned short* __restrict__ A,
                                                const unsigned short* __restrict__ Bt,
                                                unsigned short* __restrict__ P0,
                                                unsigned short* __restrict__ P1,
                                                unsigned short* __restrict__ P2,
                                                unsigned short* __restrict__ P3,
                                                int M, int N, int K, int Nt) {
    __shared__ __align__(16) unsigned short As[2][128 * 32];
    __shared__ __align__(16) unsigned short Bs[2][128 * 32];

    const int t    = threadIdx.x;
    const int lane = t & 63;
    const int w    = t >> 6;
    const int quad = lane >> 4;
    const int l16  = lane & 15;
    const int wm = (w >> 1) * 64, wn = (w & 1) * 64;

    const int lin = blockIdx.x;
    const int xcd = lin & 7, s = lin >> 3;
    const int mi = s & 3;
    const int r  = s >> 2;
    const int n0 = (r % Nt) * 128;
    const int z  = r / Nt;              // 0..3
    const int m0 = ((xcd << 2) | mi) * 128;

    const int K4 = K >> 2;
    const int kbeg = z * K4;
    unsigned short* C = (z == 0) ? P0 : (z == 1) ? P1 : (z == 2) ? P2 : P3;
    const int rowA = t >> 2, offA = (t & 3) * 8, rowA2 = rowA + 64;
    const int la0 = rowA * 32 + offA, la1 = rowA2 * 32 + offA;

    const size_t aoff0 = (size_t)(m0 + rowA)  * K + offA + kbeg;
    const size_t aoff1 = (size_t)(m0 + rowA2) * K + offA + kbeg;
    const size_t boff0 = (size_t)(n0 + rowA)  * K + offA + kbeg;
    const size_t boff1 = (size_t)(n0 + rowA2) * K + offA + kbeg;

    f32x4 acc[4][4];
#pragma unroll
    for (int i = 0; i < 4; i++)
#pragma unroll
        for (int j = 0; j < 4; j++) acc[i][j] = (f32x4){0.f, 0.f, 0.f, 0.f};

    {
        short8 ta0 = *(const short8*)&A[aoff0];
        short8 ta1 = *(const short8*)&A[aoff1];
        short8 tb0 = *(const short8*)&Bt[boff0];
        short8 tb1 = *(const short8*)&Bt[boff1];
        *(short8*)&As[0][la0] = ta0;
        *(short8*)&As[0][la1] = ta1;
        *(short8*)&Bs[0][la0] = tb0;
        *(short8*)&Bs[0][la1] = tb1;
    }
    short8 ca0, ca1, cb0, cb1;
    if (32 < K4) {
        ca0 = *(const short8*)&A[aoff0 + 32];
        ca1 = *(const short8*)&A[aoff1 + 32];
        cb0 = *(const short8*)&Bt[boff0 + 32];
        cb1 = *(const short8*)&Bt[boff1 + 32];
    }
    __syncthreads();

    int p = 0;
    for (int k0 = 0; k0 < K4; k0 += 32, p ^= 1) {
        short8 na0, na1, nb0, nb1;
        const bool have2 = (k0 + 64 < K4);
        const bool have1 = (k0 + 32 < K4);
        if (have2) {
            na0 = *(const short8*)&A[aoff0 + k0 + 64];
            na1 = *(const short8*)&A[aoff1 + k0 + 64];
            nb0 = *(const short8*)&Bt[boff0 + k0 + 64];
            nb1 = *(const short8*)&Bt[boff1 + k0 + 64];
        }
        if (have1) {
            *(short8*)&As[p ^ 1][la0] = ca0;
            *(short8*)&As[p ^ 1][la1] = ca1;
            *(short8*)&Bs[p ^ 1][la0] = cb0;
            *(short8*)&Bs[p ^ 1][la1] = cb1;
        }

        bf16x8 af[4], bfv[4];
#pragma unroll
        for (int i = 0; i < 4; i++)
            af[i] = *(const bf16x8*)&As[p][(wm + i * 16 + l16) * 32 + quad * 8];
#pragma unroll
        for (int j = 0; j < 4; j++)
            bfv[j] = *(const bf16x8*)&Bs[p][(wn + j * 16 + l16) * 32 + quad * 8];
#pragma unroll
        for (int i = 0; i < 4; i++)
#pragma unroll
            for (int j = 0; j < 4; j++)
                acc[i][j] = __builtin_amdgcn_mfma_f32_16x16x32_bf16(af[i], bfv[j], acc[i][j], 0, 0, 0);

        __syncthreads();
        if (have2) { ca0 = na0; ca1 = na1; cb0 = nb0; cb1 = nb1; }
    }

#pragma unroll
    for (int j = 0; j < 4; j++) {
        int col = n0 + wn + j * 16 + l16;
#pragma unroll
        for (int i = 0; i < 4; i++) {
            int rowb = m0 + wm + i * 16 + quad * 4;
#pragma unroll
            for (int r2 = 0; r2 < 4; r2++)
                C[(size_t)(rowb + r2) * N + col] = f2bf(acc[i][j][r2]);
        }
    }
}

// ---------------------------------------------------------------------------
// MFMA flash attention v5 (unchanged from R9).
// ---------------------------------------------------------------------------
__global__ __launch_bounds__(256, 3) void attn_mfma(const unsigned short* __restrict__ qkv,
                                                    const unsigned short* __restrict__ vtg,
                                                    unsigned short* __restrict__ zb) {
    __shared__ __align__(16) unsigned short ks[2][64 * APAD];
    __shared__ __align__(16) unsigned short vt[64 * APAD];
    __shared__ __align__(16) unsigned short ps[128 * APAD];

    const int t    = threadIdx.x;
    const int lane = t & 63;
    const int w    = t >> 6;
    const int l16  = lane & 15;
    const int quad = lane >> 4;

    const int lin  = blockIdx.x;
    const int xcd  = lin & 7;
    const int s    = lin >> 3;
    const int hh   = xcd * 2 + (s & 1);
    const int rest = s >> 1;
    const int b    = rest & 1;
    const int qq0  = rest >> 1;
    const int qq   = b ? qq0 : 15 - qq0;

    const size_t rowbase = (size_t)b * L_;
    const size_t vbase   = ((size_t)(b * H_ + hh) * 64) * (size_t)L_;

    bf16x8 qf[2][2];
#pragma unroll
    for (int g = 0; g < 2; g++) {
        size_t qrow = rowbase + qq * 128 + w * 32 + g * 16 + l16;
#pragma unroll
        for (int c = 0; c < 2; c++)
            qf[g][c] = *(const bf16x8*)&qkv[qrow * 3072 + hh * 64 + c * 32 + quad * 8];
    }

    f32x4 o[2][4];
#pragma unroll
    for (int g = 0; g < 2; g++)
#pragma unroll
        for (int j = 0; j < 4; j++) o[g][j] = (f32x4){0.f, 0.f, 0.f, 0.f};
    float l_i[2][4] = {};

    const int rr0 = t >> 3, o8 = (t & 7) * 8, rr1 = rr0 + 32;
    const int ktmax = 2 * qq + 1;

    {   // preload tile 0
        size_t kg = rowbase * 3072 + 1024 + hh * 64;
        short8 k0 = *(const short8*)&qkv[kg + (size_t)rr0 * 3072 + o8];
        short8 k1 = *(const short8*)&qkv[kg + (size_t)rr1 * 3072 + o8];
        short8 v0 = *(const short8*)&vtg[vbase + (size_t)rr0 * L_ + o8];
        short8 v1 = *(const short8*)&vtg[vbase + (size_t)rr1 * L_ + o8];
        *(short8*)&ks[0][rr0 * APAD + o8] = k0;
        *(short8*)&ks[0][rr1 * APAD + o8] = k1;
        *(short8*)&vt[rr0 * APAD + o8] = v0;
        *(short8*)&vt[rr1 * APAD + o8] = v1;
    }

    short8 kr0, kr1, vr0, vr1;
    for (int kt = 0; kt <= ktmax; kt++) {
        const int p = kt & 1;
        __syncthreads();

        if (kt < ktmax) {
            size_t kg = (rowbase + (kt + 1) * 64) * 3072 + 1024 + hh * 64;
            kr0 = *(const short8*)&qkv[kg + (size_t)rr0 * 3072 + o8];
            kr1 = *(const short8*)&qkv[kg + (size_t)rr1 * 3072 + o8];
            size_t vg = vbase + (kt + 1) * 64;
            vr0 = *(const short8*)&vtg[vg + (size_t)rr0 * L_ + o8];
            vr1 = *(const short8*)&vtg[vg + (size_t)rr1 * L_ + o8];
        }

        f32x4 s4[2][4];
#pragma unroll
        for (int g = 0; g < 2; g++)
#pragma unroll
            for (int j = 0; j < 4; j++) s4[g][j] = (f32x4){0.f, 0.f, 0.f, 0.f};
#pragma unroll
        for (int c = 0; c < 2; c++)
#pragma unroll
            for (int j = 0; j < 4; j++) {
                bf16x8 kf = *(const bf16x8*)&ks[p][(j * 16 + l16) * APAD + c * 32 + quad * 8];
#pragma unroll
                for (int g = 0; g < 2; g++)
                    s4[g][j] = __builtin_amdgcn_mfma_f32_16x16x32_bf16(qf[g][c], kf, s4[g][j], 0, 0, 0);
            }

        if (kt >= 2 * qq) {
#pragma unroll
            for (int g = 0; g < 2; g++)
#pragma unroll
                for (int j = 0; j < 4; j++) {
                    int lk = kt * 64 + j * 16 + l16;
#pragma unroll
                    for (int r = 0; r < 4; r++)
                        if (lk > qq * 128 + w * 32 + g * 16 + quad * 4 + r)
                            s4[g][j][r] = -INFINITY;
                }
        }

#pragma unroll
        for (int g = 0; g < 2; g++)
#pragma unroll
            for (int r = 0; r < 4; r++) {
                float p0 = __builtin_amdgcn_exp2f(s4[g][0][r]);
                float p1 = __builtin_amdgcn_exp2f(s4[g][1][r]);
                float p2 = __builtin_amdgcn_exp2f(s4[g][2][r]);
                float p3 = __builtin_amdgcn_exp2f(s4[g][3][r]);
                l_i[g][r] += (p0 + p1) + (p2 + p3);
                uint2 pk = { pk_trunc(p0, p1), pk_trunc(p2, p3) };
                *(uint2*)&ps[(w * 32 + g * 16 + quad * 4 + r) * APAD + 4 * l16] = pk;
            }

        __builtin_amdgcn_s_waitcnt(0xc07f);

#pragma unroll
        for (int c = 0; c < 2; c++) {
            bf16x8 pf[2];
#pragma unroll
            for (int g = 0; g < 2; g++)
                pf[g] = *(const bf16x8*)&ps[(w * 32 + g * 16 + l16) * APAD + c * 32 + quad * 8];
#pragma unroll
            for (int j = 0; j < 4; j++) {
                bf16x8 vf = *(const bf16x8*)&vt[(j * 16 + l16) * APAD + c * 32 + quad * 8];
#pragma unroll
                for (int g = 0; g < 2; g++)
                    o[g][j] = __builtin_amdgcn_mfma_f32_16x16x32_bf16(pf[g], vf, o[g][j], 0, 0, 0);
            }
        }

        __syncthreads();
        if (kt < ktmax) {
            *(short8*)&ks[p ^ 1][rr0 * APAD + o8] = kr0;
            *(short8*)&ks[p ^ 1][rr1 * APAD + o8] = kr1;
            *(short8*)&vt[rr0 * APAD + o8] = vr0;
            *(short8*)&vt[rr1 * APAD + o8] = vr1;
        }
    }

#pragma unroll
    for (int g = 0; g < 2; g++)
#pragma unroll
        for (int r = 0; r < 4; r++) {
            float l = l_i[g][r];
            l += __shfl_xor(l, 1);
            l += __shfl_xor(l, 2);
            l += __shfl_xor(l, 4);
            l += __shfl_xor(l, 8);
            float inv = 1.f / l;
            size_t row = rowbase + qq * 128 + w * 32 + g * 16 + quad * 4 + r;
#pragma unroll
            for (int j = 0; j < 4; j++)
                zb[row * 1024 + hh * 64 + j * 16 + l16] = f2bf(o[g][j][r] * inv);
        }
}

// ---------------------------------------------------------------------------
// LayerNorm(a + sum of 4 bf16 partial planes + bias) * g + beta.
// ---------------------------------------------------------------------------
template <int WRITE_BF16>
__global__ __launch_bounds__(256) void ln5_kernel(const float* __restrict__ a,
                                                  const unsigned short* __restrict__ q0,
                                                  const unsigned short* __restrict__ q1,
                                                  const unsigned short* __restrict__ q2,
                                                  const unsigned short* __restrict__ q3,
                                                  const float* __restrict__ bias,
                                                  const float* __restrict__ g,
                                                  const float* __restrict__ be,
                                                  float* __restrict__ out,
                                                  unsigned short* __restrict__ out_bf) {
    __shared__ float s1[256], s2[256];
    const int row = blockIdx.x;
    const int t   = threadIdx.x;
    const size_t base = (size_t)row * E_ + t * 4;

    float4 ya = *(const float4*)&a[base];
    ushort4 u0 = *(const ushort4*)&q0[base];
    ushort4 u1 = *(const ushort4*)&q1[base];
    ushort4 u2 = *(const ushort4*)&q2[base];
    ushort4 u3 = *(const ushort4*)&q3[base];
    float4 bb = *(const float4*)&bias[t * 4];
    float y0 = ya.x + bb.x + bf2f(u0.x) + bf2f(u1.x) + bf2f(u2.x) + bf2f(u3.x);
    float y1 = ya.y + bb.y + bf2f(u0.y) + bf2f(u1.y) + bf2f(u2.y) + bf2f(u3.y);
    float y2 = ya.z + bb.z + bf2f(u0.z) + bf2f(u1.z) + bf2f(u2.z) + bf2f(u3.z);
    float y3 = ya.w + bb.w + bf2f(u0.w) + bf2f(u1.w) + bf2f(u2.w) + bf2f(u3.w);

    s1[t] = y0 + y1 + y2 + y3;
    s2[t] = y0 * y0 + y1 * y1 + y2 * y2 + y3 * y3;
    __syncthreads();
    for (int off = 128; off > 0; off >>= 1) {
        if (t < off) { s1[t] += s1[t + off]; s2[t] += s2[t + off]; }
        __syncthreads();
    }
    float mean = s1[0] * (1.0f / E_);
    float var  = s2[0] * (1.0f / E_) - mean * mean;
    float rstd = rsqrtf(var + 1e-5f);

    float4 gv = *(const float4*)&g[t * 4];
    float4 bv = *(const float4*)&be[t * 4];
    float4 ov;
    ov.x = (y0 - mean) * rstd * gv.x + bv.x;
    ov.y = (y1 - mean) * rstd * gv.y + bv.y;
    ov.z = (y2 - mean) * rstd * gv.z + bv.z;
    ov.w = (y3 - mean) * rstd * gv.w + bv.w;
    *(float4*)&out[base] = ov;
    if (WRITE_BF16) {
        ushort4 pk = { f2bf(ov.x), f2bf(ov.y), f2bf(ov.z), f2bf(ov.w) };
        *(ushort4*)&out_bf[base] = pk;
    }
}

// ---------------------------------------------------------------------------
extern "C" void kernel_launch(void* const* d_in, const int* in_sizes, int n_in,
                              void* d_out, int out_size, void* d_ws, size_t ws_size,
                              hipStream_t stream)
{
    const float* x     = (const float*)d_in[0];
    const float* Wq    = (const float*)d_in[2];
    const float* bq    = (const float*)d_in[3];
    const float* Wk    = (const float*)d_in[4];
    const float* bk    = (const float*)d_in[5];
    const float* Wv    = (const float*)d_in[6];
    const float* bv    = (const float*)d_in[7];
    const float* Wo    = (const float*)d_in[8];
    const float* bo    = (const float*)d_in[9];
    const float* W1    = (const float*)d_in[10];
    const float* c1    = (const float*)d_in[11];
    const float* W2    = (const float*)d_in[12];
    const float* c2    = (const float*)d_in[13];
    const float* g1    = (const float*)d_in[14];
    const float* beta1 = (const float*)d_in[15];
    const float* g2    = (const float*)d_in[16];
    const float* beta2 = (const float*)d_in[17];
    float* out = (float*)d_out;

    const size_t MB = 1024 * 1024;
    char* w = (char*)d_ws;
    unsigned short* xb    = (unsigned short*)(w + 0 * MB);    // [0,8)   prep..QKV
    unsigned short* Wqkvt = (unsigned short*)(w + 8 * MB);    // [8,14)
    unsigned short* Wot   = (unsigned short*)(w + 14 * MB);   // [14,16)
    unsigned short* W1t   = (unsigned short*)(w + 16 * MB);   // [16,24)
    unsigned short* W2t   = (unsigned short*)(w + 24 * MB);   // [24,32)
    float*          bqkv  = (float*)(w + 32 * MB);            // [32,33)
    unsigned short* qkv   = (unsigned short*)(w + 33 * MB);   // [33,57)  QKV..attn
    unsigned short* zb    = (unsigned short*)(w + 57 * MB);   // [57,65)  attn..Wo
    float*          h     = (float*)(w + 65 * MB);            // [65,81)  LN1..LN2
    unsigned short* vtg   = (unsigned short*)(w + 89 * MB);   // [89,97)  vT..attn
    unsigned short* ap0   = (unsigned short*)(w + 33 * MB);
    unsigned short* ap1   = (unsigned short*)(w + 41 * MB);
    unsigned short* ap2   = (unsigned short*)(w + 49 * MB);
    unsigned short* ap3   = (unsigned short*)(w + 89 * MB);
    unsigned short* hb    = (unsigned short*)(w + 0 * MB);    // LN1..FFN1 (over xb)
    unsigned short* ff1b  = (unsigned short*)(w + 33 * MB);   // FFN1..FFN2 [33,65)
    unsigned short* fp0   = (unsigned short*)(w + 0 * MB);
    unsigned short* fp1   = (unsigned short*)(w + 8 * MB);
    unsigned short* fp2   = (unsigned short*)(w + 16 * MB);
    unsigned short* fp3   = (unsigned short*)(w + 81 * MB);

    dim3 blk(256);

    prep<<<dim3(16396), blk, 0, stream>>>(x, Wq, Wk, Wv, bq, bk, bv, Wo, W1, W2,
                                          xb, Wqkvt, Wot, W1t, W2t, bqkv);

    // QKV: N=3072 -> 24 n-tiles, grid 24*32 = 768
    gemm_bt<0, 1><<<dim3(768), blk, 0, stream>>>(xb, Wqkvt, bqkv, qkv, M_, 3072, E_);

    v_transpose_perm<<<dim3(L_ / 64, H_, B_), blk, 0, stream>>>(qkv, vtg);

    attn_mfma<<<dim3(512), blk, 0, stream>>>(qkv, vtg, zb);

    // Wo: N=1024 -> 8 n-tiles, split-K=4, grid 8*32*4 = 1024
    gemm_sk4<<<dim3(1024), blk, 0, stream>>>(zb, Wot, ap0, ap1, ap2, ap3, M_, E_, E_, 8);

    ln5_kernel<1><<<dim3(M_), blk, 0, stream>>>(x, ap0, ap1, ap2, ap3, bo, g1, beta1, h, hb);

    // FFN1: N=4096 -> 32 n-tiles, grid 32*32 = 1024
    gemm_bt<1, 1><<<dim3(1024), blk, 0, stream>>>(hb, W1t, c1, ff1b, M_, DFF, E_);

    // FFN2: N=1024 -> 8 n-tiles, split-K=4, grid 1024
    gemm_sk4<<<dim3(1024), blk, 0, stream>>>(ff1b, W2t, fp0, fp1, fp2, fp3, M_, E_, DFF, 8);

    ln5_kernel<0><<<dim3(M_), blk, 0, stream>>>(h, fp0, fp1, fp2, fp3, c2, g2, beta2, out, nullptr);
}